// Round 8
// baseline (190.552 us; speedup 1.0000x reference)
//
#include <hip/hip_runtime.h>
#include <stdint.h>

// B=4, S=1024, E=1024, H=16, dh=64
// ws layout (shorts): Xbf/Obf @0 (12.58M), Wqb @12582912 (1M), Wob @13631488 (1M),
//                     qkv @14680064 (12.58M: Q [B][H][S][64], K same +4M, V^T [B][H][64][S] +8M)

typedef __attribute__((ext_vector_type(8))) short bf16x8;
typedef __attribute__((ext_vector_type(4))) float f32x4;
typedef __attribute__((ext_vector_type(4))) short short4v;

#define GLOAD_LDS(gp, lp)                                                      \
  __builtin_amdgcn_global_load_lds(                                            \
      (__attribute__((address_space(1))) void*)(gp),                           \
      (__attribute__((address_space(3))) void*)(lp), 16, 0, 0)

__device__ __forceinline__ unsigned short f2bf(float f) {
  union { float f; unsigned u; } v; v.f = f;
  unsigned r = v.u + 0x7FFFu + ((v.u >> 16) & 1u);
  return (unsigned short)(r >> 16);
}
// cheap round-half-up for P values (nonneg, feeds MFMA; 1 VALU op vs 3)
__device__ __forceinline__ unsigned short f2bf_fast(float f) {
  union { float f; unsigned u; } v; v.f = f;
  return (unsigned short)((v.u + 0x8000u) >> 16);
}

// DPP row_ror:N within each 16-lane row — VALU cross-lane, no DS pipe.
template<int CTRL>
__device__ __forceinline__ float dpp_rr(float x) {
  union { float f; int i; } a, r;
  a.f = x;
  r.i = __builtin_amdgcn_update_dpp(0, a.i, CTRL, 0xf, 0xf, false);
  return r.f;
}
__device__ __forceinline__ float rowmax16(float x) {
  x = fmaxf(x, dpp_rr<0x121>(x));
  x = fmaxf(x, dpp_rr<0x122>(x));
  x = fmaxf(x, dpp_rr<0x124>(x));
  x = fmaxf(x, dpp_rr<0x128>(x));
  return x;
}

// ---------- fp32 -> bf16 convert: all 5 tensors in ONE launch --------------
__global__ void cvt_all(const float* __restrict__ q, const float* __restrict__ k,
                        const float* __restrict__ v, const float* __restrict__ wq,
                        const float* __restrict__ wo, short* __restrict__ dst) {
  int i = blockIdx.x * 256 + threadIdx.x;
  const float* src; int j;
  if (i < 1048576)      { src = q;  j = i; }
  else if (i < 2097152) { src = k;  j = i - 1048576; }
  else if (i < 3145728) { src = v;  j = i - 2097152; }
  else if (i < 3407872) { src = wq; j = i - 3145728; }
  else                  { src = wo; j = i - 3407872; }
  float4 f = reinterpret_cast<const float4*>(src)[j];
  short4v o;
  o.x = (short)f2bf(f.x); o.y = (short)f2bf(f.y);
  o.z = (short)f2bf(f.z); o.w = (short)f2bf(f.w);
  reinterpret_cast<short4v*>(dst)[i] = o;
}

// ---------------- bf16 GEMM  C = A[M,1024] * W[1024,1024]^T + bias ---------
template<int EPI>
__global__ __launch_bounds__(256, 2)
void gemm_bt(const short* __restrict__ A, const short* __restrict__ Bw,
             const float* __restrict__ bias,
             short* __restrict__ qkv, float* __restrict__ outf)
{
  __shared__ short As[128 * 64];
  __shared__ short Bs[128 * 64];
  const int tid  = threadIdx.x;
  const int lane = tid & 63;
  const int g    = lane >> 4;     // 16-lane group 0..3
  const int r7   = lane & 7;
  const int w    = tid >> 6;      // wave 0..3
  const int wm   = w >> 1, wn = w & 1;

  // XCD-aware bijective swizzle (nwg%8==0)
  const int orig = blockIdx.y * 8 + blockIdx.x;
  const int cpx  = (gridDim.x * gridDim.y) >> 3;
  const int t    = (orig & 7) * cpx + (orig >> 3);
  const int m0   = (t >> 3) * 128, n0 = (t & 7) * 128;

  f32x4 acc[4][4] = {};

  for (int k0 = 0; k0 < 1024; k0 += 64) {
#pragma unroll
    for (int c = 0; c < 4; c++) {
      int L   = c * 256 + tid;
      int row = L >> 3;
      int col = ((L & 7) ^ (row & 7)) * 8;
      GLOAD_LDS(A  + (m0 + row) * 1024 + k0 + col, As + L * 8);
      GLOAD_LDS(Bw + (n0 + row) * 1024 + k0 + col, Bs + L * 8);
    }
    __syncthreads();
#pragma unroll
    for (int kk = 0; kk < 2; kk++) {
      bf16x8 av[4], bv[4];
#pragma unroll
      for (int mi = 0; mi < 4; mi++) {
        int row = wm * 64 + mi * 16 + (lane & 15);
        av[mi] = *(const bf16x8*)&As[row * 64 + (((kk * 4 + g) ^ r7) * 8)];
      }
#pragma unroll
      for (int ni = 0; ni < 4; ni++) {
        int row = wn * 64 + ni * 16 + (lane & 15);
        bv[ni] = *(const bf16x8*)&Bs[row * 64 + (((kk * 4 + g) ^ r7) * 8)];
      }
#pragma unroll
      for (int mi = 0; mi < 4; mi++)
#pragma unroll
        for (int ni = 0; ni < 4; ni++)
          acc[mi][ni] = __builtin_amdgcn_mfma_f32_16x16x32_bf16(av[mi], bv[ni], acc[mi][ni], 0, 0, 0);
    }
    __syncthreads();
  }

  if (EPI == 0) {
    const int inp = m0 >> 12;  // 0=q,1=k,2=v (block never straddles inputs)
#pragma unroll
    for (int mi = 0; mi < 4; mi++) {
#pragma unroll
      for (int ni = 0; ni < 4; ni++) {
        const int coll = n0 + wn * 64 + ni * 16 + (lane & 15);
        const float bv = bias[coll];
        const int rbase = m0 + wm * 64 + mi * 16 + (lane >> 4) * 4;
        const int hh = coll >> 6, d = coll & 63;
        if (inp < 2) {
#pragma unroll
          for (int j = 0; j < 4; j++) {
            int rowl = rbase + j;
            int bb = (rowl >> 10) & 3, s = rowl & 1023;
            qkv[(((inp * 4 + bb) * 16 + hh) * 1024 + s) * 64 + d] =
                (short)f2bf(acc[mi][ni][j] + bv);
          }
        } else {
          int bb = (rbase >> 10) & 3, s0 = rbase & 1023;
          short4v o;
          o.x = (short)f2bf(acc[mi][ni][0] + bv);
          o.y = (short)f2bf(acc[mi][ni][1] + bv);
          o.z = (short)f2bf(acc[mi][ni][2] + bv);
          o.w = (short)f2bf(acc[mi][ni][3] + bv);
          *(short4v*)&qkv[8 * 1024 * 1024 + ((bb * 16 + hh) * 64 + d) * 1024 + s0] = o;
        }
      }
    }
  } else {
#pragma unroll
    for (int mi = 0; mi < 4; mi++) {
#pragma unroll
      for (int ni = 0; ni < 4; ni++) {
        const int coll = n0 + wn * 64 + ni * 16 + (lane & 15);
        const float bv = bias[coll];
        const int rbase = m0 + wm * 64 + mi * 16 + (lane >> 4) * 4;
#pragma unroll
        for (int j = 0; j < 4; j++)
          outf[(rbase + j) * 1024 + coll] = acc[mi][ni][j] + bv;
      }
    }
  }
}

// --- flash attention, 2-phase dbuf, 32 q-rows/wave: 1 block = (b,h,128 q) --
__global__ __launch_bounds__(256, 3)
void attn_kernel(const short* __restrict__ qkv, short* __restrict__ O)
{
  __shared__ short Ks[2][64 * 64];
  __shared__ short VTs[2][64 * 64];
  __shared__ short QPs[128 * 64];  // Q tile during hoist, then per-wave P rows

  const int tid  = threadIdx.x;
  const int lane = tid & 63;
  const int l15  = lane & 15;
  const int g    = lane >> 4, r7 = lane & 7;
  const int w    = tid >> 6;

  // XCD swizzle: 512 blocks, each XCD owns 64 contiguous -> 8 (b,h) K/V sets
  const int t   = (blockIdx.x & 7) * 64 + (blockIdx.x >> 3);
  const int qt  = t & 7, hh = (t >> 3) & 15, bb = t >> 7;
  const int q0  = qt * 128;

  const short* Qg = qkv + (bb * 16 + hh) * 1024 * 64;                     // [1024][64]
  const short* Kg = qkv + 4 * 1024 * 1024 + (bb * 16 + hh) * 1024 * 64;   // [1024][64]
  const short* Vg = qkv + 8 * 1024 * 1024 + (bb * 16 + hh) * 64 * 1024;   // [64][1024]

  // prologue: stage Q tile [128][64] + K/V tile 0 (swizzled src, linear dest)
#pragma unroll
  for (int c = 0; c < 4; c++) {
    int L = c * 256 + tid;
    int row = L >> 3;
    int col = ((L & 7) ^ (row & 7)) * 8;
    GLOAD_LDS(Qg + (q0 + row) * 64 + col, QPs + L * 8);
  }
#pragma unroll
  for (int c = 0; c < 2; c++) {
    int L = c * 256 + tid;
    int row = L >> 3;
    int col = ((L & 7) ^ (row & 7)) * 8;
    GLOAD_LDS(Kg + row * 64 + col,   &Ks[0][L * 8]);
    GLOAD_LDS(Vg + row * 1024 + col, &VTs[0][L * 8]);
  }
  __syncthreads();
  bf16x8 qf[2][2];   // [h][kk]
#pragma unroll
  for (int h = 0; h < 2; h++) {
    const int qrow = w * 32 + h * 16 + l15;
    qf[h][0] = *(const bf16x8*)&QPs[qrow * 64 + ((g ^ r7) * 8)];
    qf[h][1] = *(const bf16x8*)&QPs[qrow * 64 + (((4 + g) ^ r7) * 8)];
  }
  // B-operand with bf16 1.0 in column 0 only: acc_l = P * ones_col -> row-sums
  bf16x8 vf_l = {};
  if (l15 == 0) {
#pragma unroll
    for (int x = 0; x < 8; x++) vf_l[x] = (short)0x3F80;
  }

  const float SC = 0.125f * 1.44269504f;   // 1/sqrt(dh) * log2(e)
  float m_run[2][4];
  f32x4 acc_l[2] = {};
  f32x4 acc_o[2][4] = {};
#pragma unroll
  for (int h = 0; h < 2; h++)
#pragma unroll
    for (int j = 0; j < 4; j++) m_run[h][j] = -1e30f;

  int cur = 0;
  for (int kt = 0; kt < 16; kt++) {
    // issue next tile's stage first — drains under this tile's compute
    if (kt < 15) {
#pragma unroll
      for (int c = 0; c < 2; c++) {
        int L = c * 256 + tid;
        int row = L >> 3;
        int col = ((L & 7) ^ (row & 7)) * 8;
        GLOAD_LDS(Kg + ((kt + 1) * 64 + row) * 64 + col, &Ks[cur ^ 1][L * 8]);
        GLOAD_LDS(Vg + row * 1024 + (kt + 1) * 64 + col, &VTs[cur ^ 1][L * 8]);
      }
    }

    // ---- QK^T: wave computes 32 q-rows x 64 k-cols; K frags shared h=0,1 --
    f32x4 sa[2][4] = {};
    __builtin_amdgcn_s_setprio(1);
#pragma unroll
    for (int kk = 0; kk < 2; kk++) {
#pragma unroll
      for (int ni = 0; ni < 4; ni++) {
        int krow = ni * 16 + l15;
        bf16x8 kf = *(const bf16x8*)&Ks[cur][krow * 64 + (((kk * 4 + g) ^ r7) * 8)];
        sa[0][ni] = __builtin_amdgcn_mfma_f32_16x16x32_bf16(qf[0][kk], kf, sa[0][ni], 0, 0, 0);
        sa[1][ni] = __builtin_amdgcn_mfma_f32_16x16x32_bf16(qf[1][kk], kf, sa[1][ni], 0, 0, 0);
      }
    }
    __builtin_amdgcn_s_setprio(0);

    // ---- online softmax, exp2 domain, defer-max (THR=8 in log2 units) ----
    float mtl[2][4];
#pragma unroll
    for (int h = 0; h < 2; h++)
#pragma unroll
      for (int j = 0; j < 4; j++)
        mtl[h][j] = fmaxf(fmaxf(sa[h][0][j], sa[h][1][j]),
                          fmaxf(sa[h][2][j], sa[h][3][j])) * SC;
    float nd = -1e30f;
#pragma unroll
    for (int h = 0; h < 2; h++)
#pragma unroll
      for (int j = 0; j < 4; j++)
        nd = fmaxf(nd, mtl[h][j] - m_run[h][j]);
    if (__any(nd > 8.0f)) {   // rare after tile 0: scores are small-variance
#pragma unroll
      for (int h = 0; h < 2; h++)
#pragma unroll
        for (int j = 0; j < 4; j++) {
          float mt = rowmax16(mtl[h][j]);
          float mn = fmaxf(m_run[h][j], mt);
          float alpha = __builtin_amdgcn_exp2f(m_run[h][j] - mn);
          m_run[h][j] = mn;
          acc_l[h][j] *= alpha;
#pragma unroll
          for (int di = 0; di < 4; di++) acc_o[h][di][j] *= alpha;
        }
    }
#pragma unroll
    for (int ni = 0; ni < 4; ni++) {
      int col = ni * 16 + l15;
#pragma unroll
      for (int h = 0; h < 2; h++)
#pragma unroll
        for (int j = 0; j < 4; j++) {
          int row = w * 32 + h * 16 + g * 4 + j;
          float p = __builtin_amdgcn_exp2f(sa[h][ni][j] * SC - m_run[h][j]);
          QPs[row * 64 + (col ^ ((row & 7) << 3))] = (short)f2bf_fast(p);
        }
    }
    // ---- PV: O[32q][64d] += P[32q][64k] * V[64k][64d]; V frags shared ----
    __builtin_amdgcn_s_setprio(1);
#pragma unroll
    for (int kk = 0; kk < 2; kk++) {
      bf16x8 pf[2];
#pragma unroll
      for (int h = 0; h < 2; h++) {
        int prow = w * 32 + h * 16 + l15;
        pf[h] = *(const bf16x8*)&QPs[prow * 64 + (((kk * 4 + g) ^ r7) * 8)];
        acc_l[h] = __builtin_amdgcn_mfma_f32_16x16x32_bf16(pf[h], vf_l, acc_l[h], 0, 0, 0);
      }
#pragma unroll
      for (int di = 0; di < 4; di++) {
        int vrow = di * 16 + l15;
        bf16x8 vf = *(const bf16x8*)&VTs[cur][vrow * 64 + (((kk * 4 + g) ^ r7) * 8)];
        acc_o[0][di] = __builtin_amdgcn_mfma_f32_16x16x32_bf16(pf[0], vf, acc_o[0][di], 0, 0, 0);
        acc_o[1][di] = __builtin_amdgcn_mfma_f32_16x16x32_bf16(pf[1], vf, acc_o[1][di], 0, 0, 0);
      }
    }
    __builtin_amdgcn_s_setprio(0);
    __syncthreads();   // drains vmcnt: next tile staged; buf[cur] free for reuse
    cur ^= 1;
  }

  // l lives in C-col 0 (lanes l15==0): broadcast within 16-lane row + invert
  float linv[2][4];
#pragma unroll
  for (int h = 0; h < 2; h++)
#pragma unroll
    for (int j = 0; j < 4; j++) {
      float lv = __shfl(acc_l[h][j], lane & 48);   // src lane g*16+0
      linv[h][j] = 1.0f / lv;
    }

  // write O [b][s][h*64+d] bf16
#pragma unroll
  for (int h = 0; h < 2; h++)
#pragma unroll
    for (int di = 0; di < 4; di++) {
      int d = hh * 64 + di * 16 + l15;
#pragma unroll
      for (int j = 0; j < 4; j++) {
        int q = q0 + w * 32 + h * 16 + g * 4 + j;
        O[(bb * 1024 + q) * 1024 + d] = (short)f2bf(acc_o[h][di][j] * linv[h][j]);
      }
    }
}

extern "C" void kernel_launch(void* const* d_in, const int* in_sizes, int n_in,
                              void* d_out, int out_size, void* d_ws, size_t ws_size,
                              hipStream_t stream)
{
  (void)in_sizes; (void)n_in; (void)out_size; (void)ws_size;
  const float* q    = (const float*)d_in[0];
  const float* k    = (const float*)d_in[1];
  const float* v    = (const float*)d_in[2];
  const float* Wq_w = (const float*)d_in[3];
  const float* Wq_b = (const float*)d_in[4];
  const float* Wo_w = (const float*)d_in[5];
  const float* Wo_b = (const float*)d_in[6];
  float* out = (float*)d_out;

  short* ws   = (short*)d_ws;
  short* Xbf  = ws;                 // [3*4096][1024] bf16 (q,k,v inputs; Wqb/Wob follow)
  short* Obf  = ws;                 // aliases Xbf (dead after proj GEMM)
  short* Wqb  = ws + 12582912;
  short* Wob  = ws + 13631488;
  short* qkv  = ws + 14680064;

  cvt_all<<<14336, 256, 0, stream>>>(q, k, v, Wq_w, Wo_w, ws);

  dim3 gp(8, 96);   // N/128=8, M/128=96  (q,k,v batched: same Wq per reference bug)
  gemm_bt<0><<<gp, 256, 0, stream>>>(Xbf, Wqb, Wq_b, qkv, nullptr);

  attn_kernel<<<512, 256, 0, stream>>>(qkv, Obf);

  dim3 gf(8, 32);
  gemm_bt<1><<<gf, 256, 0, stream>>>(Obf, Wob, Wo_b, nullptr, out);
}

// Round 9
// 189.403 us; speedup vs baseline: 1.0061x; 1.0061x over previous
//
#include <hip/hip_runtime.h>
#include <stdint.h>

// B=4, S=1024, E=1024, H=16, dh=64
// ws layout (shorts): Xbf/Obf @0 (12.58M), Wqb @12582912 (1M), Wob @13631488 (1M),
//                     qkv @14680064 (12.58M: Q [B][H][S][64], K same +4M, V^T [B][H][64][S] +8M)

typedef __attribute__((ext_vector_type(8))) short bf16x8;
typedef __attribute__((ext_vector_type(4))) float f32x4;
typedef __attribute__((ext_vector_type(4))) short short4v;

#define GLOAD_LDS(gp, lp)                                                      \
  __builtin_amdgcn_global_load_lds(                                            \
      (__attribute__((address_space(1))) void*)(gp),                           \
      (__attribute__((address_space(3))) void*)(lp), 16, 0, 0)

__device__ __forceinline__ unsigned short f2bf(float f) {
  union { float f; unsigned u; } v; v.f = f;
  unsigned r = v.u + 0x7FFFu + ((v.u >> 16) & 1u);
  return (unsigned short)(r >> 16);
}
// pack two f32 -> one u32 of 2 bf16 (RNE), single instruction
__device__ __forceinline__ unsigned cvt_pk_bf16(float lo, float hi) {
  unsigned r;
  asm("v_cvt_pk_bf16_f32 %0, %1, %2" : "=v"(r) : "v"(lo), "v"(hi));
  return r;
}

// ---------- fp32 -> bf16 convert: all 5 tensors in ONE launch --------------
__global__ void cvt_all(const float* __restrict__ q, const float* __restrict__ k,
                        const float* __restrict__ v, const float* __restrict__ wq,
                        const float* __restrict__ wo, short* __restrict__ dst) {
  int i = blockIdx.x * 256 + threadIdx.x;
  const float* src; int j;
  if (i < 1048576)      { src = q;  j = i; }
  else if (i < 2097152) { src = k;  j = i - 1048576; }
  else if (i < 3145728) { src = v;  j = i - 2097152; }
  else if (i < 3407872) { src = wq; j = i - 3145728; }
  else                  { src = wo; j = i - 3407872; }
  float4 f = reinterpret_cast<const float4*>(src)[j];
  short4v o;
  o.x = (short)f2bf(f.x); o.y = (short)f2bf(f.y);
  o.z = (short)f2bf(f.z); o.w = (short)f2bf(f.w);
  reinterpret_cast<short4v*>(dst)[i] = o;
}

// ---------------- bf16 GEMM  C = A[M,1024] * W[1024,1024]^T + bias ---------
template<int EPI>
__global__ __launch_bounds__(256, 2)
void gemm_bt(const short* __restrict__ A, const short* __restrict__ Bw,
             const float* __restrict__ bias,
             short* __restrict__ qkv, float* __restrict__ outf)
{
  __shared__ short As[128 * 64];
  __shared__ short Bs[128 * 64];
  const int tid  = threadIdx.x;
  const int lane = tid & 63;
  const int g    = lane >> 4;     // 16-lane group 0..3
  const int r7   = lane & 7;
  const int w    = tid >> 6;      // wave 0..3
  const int wm   = w >> 1, wn = w & 1;

  // XCD-aware bijective swizzle (nwg%8==0)
  const int orig = blockIdx.y * 8 + blockIdx.x;
  const int cpx  = (gridDim.x * gridDim.y) >> 3;
  const int t    = (orig & 7) * cpx + (orig >> 3);
  const int m0   = (t >> 3) * 128, n0 = (t & 7) * 128;

  f32x4 acc[4][4] = {};

  for (int k0 = 0; k0 < 1024; k0 += 64) {
#pragma unroll
    for (int c = 0; c < 4; c++) {
      int L   = c * 256 + tid;
      int row = L >> 3;
      int col = ((L & 7) ^ (row & 7)) * 8;
      GLOAD_LDS(A  + (m0 + row) * 1024 + k0 + col, As + L * 8);
      GLOAD_LDS(Bw + (n0 + row) * 1024 + k0 + col, Bs + L * 8);
    }
    __syncthreads();
#pragma unroll
    for (int kk = 0; kk < 2; kk++) {
      bf16x8 av[4], bv[4];
#pragma unroll
      for (int mi = 0; mi < 4; mi++) {
        int row = wm * 64 + mi * 16 + (lane & 15);
        av[mi] = *(const bf16x8*)&As[row * 64 + (((kk * 4 + g) ^ r7) * 8)];
      }
#pragma unroll
      for (int ni = 0; ni < 4; ni++) {
        int row = wn * 64 + ni * 16 + (lane & 15);
        bv[ni] = *(const bf16x8*)&Bs[row * 64 + (((kk * 4 + g) ^ r7) * 8)];
      }
#pragma unroll
      for (int mi = 0; mi < 4; mi++)
#pragma unroll
        for (int ni = 0; ni < 4; ni++)
          acc[mi][ni] = __builtin_amdgcn_mfma_f32_16x16x32_bf16(av[mi], bv[ni], acc[mi][ni], 0, 0, 0);
    }
    __syncthreads();
  }

  if (EPI == 0) {
    const int inp = m0 >> 12;  // 0=q,1=k,2=v (block never straddles inputs)
#pragma unroll
    for (int mi = 0; mi < 4; mi++) {
#pragma unroll
      for (int ni = 0; ni < 4; ni++) {
        const int coll = n0 + wn * 64 + ni * 16 + (lane & 15);
        const float bv = bias[coll];
        const int rbase = m0 + wm * 64 + mi * 16 + (lane >> 4) * 4;
        const int hh = coll >> 6, d = coll & 63;
        if (inp < 2) {
#pragma unroll
          for (int j = 0; j < 4; j++) {
            int rowl = rbase + j;
            int bb = (rowl >> 10) & 3, s = rowl & 1023;
            qkv[(((inp * 4 + bb) * 16 + hh) * 1024 + s) * 64 + d] =
                (short)f2bf(acc[mi][ni][j] + bv);
          }
        } else {
          int bb = (rbase >> 10) & 3, s0 = rbase & 1023;
          short4v o;
          o.x = (short)f2bf(acc[mi][ni][0] + bv);
          o.y = (short)f2bf(acc[mi][ni][1] + bv);
          o.z = (short)f2bf(acc[mi][ni][2] + bv);
          o.w = (short)f2bf(acc[mi][ni][3] + bv);
          *(short4v*)&qkv[8 * 1024 * 1024 + ((bb * 16 + hh) * 64 + d) * 1024 + s0] = o;
        }
      }
    }
  } else {
#pragma unroll
    for (int mi = 0; mi < 4; mi++) {
#pragma unroll
      for (int ni = 0; ni < 4; ni++) {
        const int coll = n0 + wn * 64 + ni * 16 + (lane & 15);
        const float bv = bias[coll];
        const int rbase = m0 + wm * 64 + mi * 16 + (lane >> 4) * 4;
#pragma unroll
        for (int j = 0; j < 4; j++)
          outf[(rbase + j) * 1024 + coll] = acc[mi][ni][j] + bv;
      }
    }
  }
}

// --- flash attention, swapped-operand (T12): lane owns one q-row ----------
// 1 block = (b,h,64 q), 4 waves x 16 q-rows; P packed in-reg, tiny LDS bounce
__global__ __launch_bounds__(256, 4)
void attn_kernel(const short* __restrict__ qkv, short* __restrict__ O)
{
  __shared__ __align__(16) short Qs[64 * 64];       // Q stage; then per-wave Pt
  __shared__ __align__(16) short Ks[2][64 * 64];
  __shared__ __align__(16) short VTs[2][64 * 64];

  const int tid  = threadIdx.x;
  const int lane = tid & 63;
  const int l15  = lane & 15;
  const int g    = lane >> 4, r7 = lane & 7;
  const int w    = tid >> 6;

  // XCD swizzle: each XCD owns 128 contiguous -> 8 (b,h) K/V sets (L2-fits)
  const int t   = (blockIdx.x & 7) * 128 + (blockIdx.x >> 3);
  const int qt  = t & 15, hh = (t >> 4) & 15, bb = t >> 8;
  const int q0  = qt * 64;

  const short* Qg = qkv + (bb * 16 + hh) * 1024 * 64;                     // [1024][64]
  const short* Kg = qkv + 4 * 1024 * 1024 + (bb * 16 + hh) * 1024 * 64;   // [1024][64]
  const short* Vg = qkv + 8 * 1024 * 1024 + (bb * 16 + hh) * 64 * 1024;   // [64][1024]

  // prologue: stage Q tile [64][64] + K/V tile 0 (swizzled src, linear dest)
#pragma unroll
  for (int c = 0; c < 2; c++) {
    int L = c * 256 + tid;
    int row = L >> 3;
    int col = ((L & 7) ^ (row & 7)) * 8;
    GLOAD_LDS(Qg + (q0 + row) * 64 + col, Qs + L * 8);
    GLOAD_LDS(Kg + row * 64 + col,        &Ks[0][L * 8]);
    GLOAD_LDS(Vg + row * 1024 + col,      &VTs[0][L * 8]);
  }
  __syncthreads();
  // hoist this wave's Q fragment (B-operand; same per-lane layout as A-frag)
  bf16x8 qf[2];
  {
    const int qrow = w * 16 + l15;
    qf[0] = *(const bf16x8*)&Qs[qrow * 64 + ((g ^ r7) * 8)];
    qf[1] = *(const bf16x8*)&Qs[qrow * 64 + (((4 + g) ^ r7) * 8)];
  }
  __syncthreads();   // Qs safe to reuse as Pt after every wave hoisted

  // per-wave Pt region: [16 q-rows][32 u32] packed bf16 P-pairs, XOR-swizzled
  unsigned* PT = reinterpret_cast<unsigned*>(Qs) + w * 512;
  const int X = (l15 & 7) << 2;   // col swizzle (bits 2-4), preserves 4-runs

  const float SC = 0.125f * 1.44269504f;   // 1/sqrt(dh) * log2(e)
  float m_run = -1e30f, l_run = 0.0f;      // scalar: lane owns q-row l15
  f32x4 acc_o[4] = {};                     // O^T: d = di*16 + g*4 + j, q = l15

  int cur = 0;
  for (int kt = 0; kt < 16; kt++) {
    if (kt < 15) {
#pragma unroll
      for (int c = 0; c < 2; c++) {
        int L = c * 256 + tid;
        int row = L >> 3;
        int col = ((L & 7) ^ (row & 7)) * 8;
        GLOAD_LDS(Kg + ((kt + 1) * 64 + row) * 64 + col, &Ks[cur ^ 1][L * 8]);
        GLOAD_LDS(Vg + row * 1024 + (kt + 1) * 64 + col, &VTs[cur ^ 1][L * 8]);
      }
    }

    // ---- QK^T swapped: sa[ni] = K_blk(ni) * Q^T -> S[k=16ni+4g+j][q=l15] --
    f32x4 sa[4] = {};
    __builtin_amdgcn_s_setprio(1);
#pragma unroll
    for (int kk = 0; kk < 2; kk++) {
#pragma unroll
      for (int ni = 0; ni < 4; ni++) {
        int krow = ni * 16 + l15;
        bf16x8 kf = *(const bf16x8*)&Ks[cur][krow * 64 + (((kk * 4 + g) ^ r7) * 8)];
        sa[ni] = __builtin_amdgcn_mfma_f32_16x16x32_bf16(kf, qf[kk], sa[ni], 0, 0, 0);
      }
    }
    __builtin_amdgcn_s_setprio(0);

    // ---- softmax: lane-local row; in-lane tree + xor16 + xor32 ----
    float mt;
    {
      float a = fmaxf(fmaxf(sa[0][0], sa[0][1]), fmaxf(sa[0][2], sa[0][3]));
      float b = fmaxf(fmaxf(sa[1][0], sa[1][1]), fmaxf(sa[1][2], sa[1][3]));
      float c = fmaxf(fmaxf(sa[2][0], sa[2][1]), fmaxf(sa[2][2], sa[2][3]));
      float d = fmaxf(fmaxf(sa[3][0], sa[3][1]), fmaxf(sa[3][2], sa[3][3]));
      mt = fmaxf(fmaxf(a, b), fmaxf(c, d)) * SC;
    }
    if (__any(mt - m_run > 8.0f)) {        // defer-max: rare after tile 0
      float x = fmaxf(mt, __shfl_xor(mt, 16));
      x = fmaxf(x, __shfl_xor(x, 32));     // full-row max (row-uniform)
      float mn = fmaxf(m_run, x);
      float alpha = __builtin_amdgcn_exp2f(m_run - mn);
      m_run = mn;
      l_run *= alpha;
#pragma unroll
      for (int di = 0; di < 4; di++)
#pragma unroll
        for (int j = 0; j < 4; j++) acc_o[di][j] *= alpha;
    }
    // p = exp2(s*SC - m); pack k-adjacent pairs; accumulate tile-sum
    float ts = 0.0f;
#pragma unroll
    for (int ni = 0; ni < 4; ni++) {
      float p0 = __builtin_amdgcn_exp2f(sa[ni][0] * SC - m_run);
      float p1 = __builtin_amdgcn_exp2f(sa[ni][1] * SC - m_run);
      float p2 = __builtin_amdgcn_exp2f(sa[ni][2] * SC - m_run);
      float p3 = __builtin_amdgcn_exp2f(sa[ni][3] * SC - m_run);
      ts += (p0 + p1) + (p2 + p3);
      unsigned u0 = cvt_pk_bf16(p0, p1);   // k = 16ni+4g, +1
      unsigned u1 = cvt_pk_bf16(p2, p3);   // k = 16ni+4g+2, +3
      // logical col kp = 8ni+2g (pair p0p1), +1 (p2p3); store swizzled
      uint2 uu; uu.x = u0; uu.y = u1;
      *reinterpret_cast<uint2*>(&PT[l15 * 32 + ((8 * ni + 2 * g) ^ X)]) = uu;
    }
    ts += __shfl_xor(ts, 16);
    ts += __shfl_xor(ts, 32);              // full-row sum (row-uniform)
    l_run += ts;

    // ---- PV swapped: acc_o[di] += V^T_blk(di) * P  (pB from Pt bounce) ----
    __builtin_amdgcn_s_setprio(1);
#pragma unroll
    for (int kk = 0; kk < 2; kk++) {
      // B-frag: P[k = kk*32+8g+2r(+1)][q=l15] = 4 consecutive kp at 16kk+4g
      bf16x8 pB = *reinterpret_cast<const bf16x8*>(&PT[l15 * 32 + ((16 * kk + 4 * g) ^ X)]);
#pragma unroll
      for (int di = 0; di < 4; di++) {
        int vrow = di * 16 + l15;
        bf16x8 vf = *(const bf16x8*)&VTs[cur][vrow * 64 + (((kk * 4 + g) ^ r7) * 8)];
        acc_o[di] = __builtin_amdgcn_mfma_f32_16x16x32_bf16(vf, pB, acc_o[di], 0, 0, 0);
      }
    }
    __builtin_amdgcn_s_setprio(0);
    __syncthreads();   // drains vmcnt: next tile staged; buf[cur] reusable
    cur ^= 1;
  }

  // epilogue: lane holds O^T column q = q0 + w*16 + l15; 4x 8B stores
  const float linv = 1.0f / l_run;
  const int q = q0 + w * 16 + l15;
#pragma unroll
  for (int di = 0; di < 4; di++) {
    short4v o;
    o.x = (short)f2bf(acc_o[di][0] * linv);
    o.y = (short)f2bf(acc_o[di][1] * linv);
    o.z = (short)f2bf(acc_o[di][2] * linv);
    o.w = (short)f2bf(acc_o[di][3] * linv);
    *(short4v*)&O[(bb * 1024 + q) * 1024 + hh * 64 + di * 16 + g * 4] = o;
  }
}

extern "C" void kernel_launch(void* const* d_in, const int* in_sizes, int n_in,
                              void* d_out, int out_size, void* d_ws, size_t ws_size,
                              hipStream_t stream)
{
  (void)in_sizes; (void)n_in; (void)out_size; (void)ws_size;
  const float* q    = (const float*)d_in[0];
  const float* k    = (const float*)d_in[1];
  const float* v    = (const float*)d_in[2];
  const float* Wq_w = (const float*)d_in[3];
  const float* Wq_b = (const float*)d_in[4];
  const float* Wo_w = (const float*)d_in[5];
  const float* Wo_b = (const float*)d_in[6];
  float* out = (float*)d_out;

  short* ws   = (short*)d_ws;
  short* Xbf  = ws;                 // [3*4096][1024] bf16 (q,k,v inputs; Wqb/Wob follow)
  short* Obf  = ws;                 // aliases Xbf (dead after proj GEMM)
  short* Wqb  = ws + 12582912;
  short* Wob  = ws + 13631488;
  short* qkv  = ws + 14680064;

  cvt_all<<<14336, 256, 0, stream>>>(q, k, v, Wq_w, Wo_w, ws);

  dim3 gp(8, 96);   // N/128=8, M/128=96  (q,k,v batched: same Wq per reference bug)
  gemm_bt<0><<<gp, 256, 0, stream>>>(Xbf, Wqb, Wq_b, qkv, nullptr);

  attn_kernel<<<1024, 256, 0, stream>>>(qkv, Obf);

  dim3 gf(8, 32);
  gemm_bt<1><<<gf, 256, 0, stream>>>(Obf, Wob, Wo_b, nullptr, out);
}